// Round 5
// baseline (221.111 us; speedup 1.0000x reference)
//
#include <hip/hip_runtime.h>
#include <math.h>

#define C 8192
#define D 1024
#define BATCH 1024
#define PM 0.95f
#define PMC 0.05f
// values pre-scaled by 8 before fp8 quant; dot comes out 64x too big.
// epilogue uses 10/64 = 0.15625 (exact in fp32).
#define INVT_SCALED 0.15625f
#define NGRAM 2080

typedef unsigned char u8;
typedef __attribute__((ext_vector_type(16))) float f32x16;

#define GLOBAL_AS(p) ((const __attribute__((address_space(1))) void*)(p))
#define LDS_AS(p) ((__attribute__((address_space(3))) void*)(p))

// ---------------------------------------------------------------------------
// EMA + fp8 quantize (r17 structure, verified: 512 blocks x 16 consecutive
// classes, wave w owns classes cb+4w..cb+4w+3 sequentially; LDS-staged
// quantize + block-cooperative coalesced writeback so each 128-B P8 line is
// written once, fully, from one block/L2). fp8 layout (512-B k-units):
//   element (row c, k) -> P8[(c>>5)*32768 + (k>>4)*512 + ((k>>3)&1)*256 + (c&31)*8 + (k&7)]
__global__ __launch_bounds__(256) void ema_split_kernel(const float* __restrict__ feat,
                                                        const int* __restrict__ labels,
                                                        const float* __restrict__ protos,
                                                        u8* __restrict__ P8,
                                                        float* __restrict__ rowsum,
                                                        float* __restrict__ out,
                                                        unsigned int* __restrict__ ticket) {
    __shared__ int sl[BATCH];
    __shared__ unsigned int sq[128][16][2];   // [piece][class-in-block][half]  16 KB
    const int t = threadIdx.x, w = t >> 6, lane = t & 63;
    const int cb = blockIdx.x * 16;

    if (blockIdx.x < 32) rowsum[blockIdx.x * 256 + t] = 0.0f;
    if (blockIdx.x == 0 && t == 0) { out[0] = 0.0f; *ticket = 0u; }

    for (int i = t; i < BATCH; i += 256) sl[i] = labels[i];
    __syncthreads();

    for (int i = 0; i < 4; ++i) {
        const int c = cb + w * 4 + i;

        float4 v[4];
        #pragma unroll
        for (int s = 0; s < 4; ++s)
            v[s] = *(const float4*)(protos + (size_t)c * D + s * 256 + lane * 4);

        for (int base = 0; base < BATCH; base += 64) {
            unsigned long long mask = __ballot(sl[base + lane] == c);
            while (mask) {
                const int b = __ffsll((long long)mask) - 1;
                mask &= mask - 1;
                const int idx = base + b;
                float ss = 0.0f;
                #pragma unroll
                for (int s = 0; s < 4; ++s) {
                    const float4 f = *(const float4*)(feat + (size_t)idx * D + s * 256 + lane * 4);
                    v[s].x = v[s].x * PM + f.x * PMC;
                    v[s].y = v[s].y * PM + f.y * PMC;
                    v[s].z = v[s].z * PM + f.z * PMC;
                    v[s].w = v[s].w * PM + f.w * PMC;
                    ss += v[s].x * v[s].x + v[s].y * v[s].y + v[s].z * v[s].z + v[s].w * v[s].w;
                }
                #pragma unroll
                for (int off = 32; off > 0; off >>= 1) ss += __shfl_xor(ss, off);
                const float inv = 1.0f / fmaxf(sqrtf(ss), 1e-12f);
                #pragma unroll
                for (int s = 0; s < 4; ++s) {
                    v[s].x *= inv; v[s].y *= inv; v[s].z *= inv; v[s].w *= inv;
                }
            }
        }

        // quantize into LDS staging: piece pp = s*32 + (lane>>1), half = lane&1
        #pragma unroll
        for (int s = 0; s < 4; ++s) {
            int p = __builtin_amdgcn_cvt_pk_fp8_f32(v[s].x * 8.0f, v[s].y * 8.0f, 0, false);
            p = __builtin_amdgcn_cvt_pk_fp8_f32(v[s].z * 8.0f, v[s].w * 8.0f, p, true);
            sq[s * 32 + (lane >> 1)][w * 4 + i][lane & 1] = (unsigned int)p;
        }
    }
    __syncthreads();

    // coalesced writeback: 1024 slots of 16 B (piece pp, class pair 2a,2a+1)
    u8* base = P8 + (size_t)(cb >> 5) * 32768 + (cb & 31) * 8;
    #pragma unroll
    for (int it = 0; it < 4; ++it) {
        const int slot = it * 256 + t;
        const int pp = slot >> 3, a = slot & 7;
        uint4 val;
        val.x = sq[pp][2 * a][0];     val.y = sq[pp][2 * a][1];
        val.z = sq[pp][2 * a + 1][0]; val.w = sq[pp][2 * a + 1][1];
        *(uint4*)(base + (pp >> 1) * 512 + (pp & 1) * 256 + a * 16) = val;
    }
}

// ---------------------------------------------------------------------------
// fp8 Gram, mfma_f32_32x32x16_fp8_fp8. r13 pipeline verbatim (best known):
// 5 LDS buffers, 40 KB, oldest-2 vmcnt waits, 4 blocks/CU, cross-barrier
// register fragment prefetch. r18 additions, separable in counters:
//  (a) T5 setprio(1) around each MFMA cluster (isolates in gram8 dur);
//  (b) final2 FUSED via completion ticket: after a block's rowsum atomics,
//      threadfence + agent-scope fetch_add; ticket 2079 (last of NGRAM)
//      re-reads rowsum with agent-scope atomic loads (coherent: all writers
//      used device atomics) and computes out = mean(log(rowsum/(C-1))).
//      Saves one kernel launch + final2's ~3 us (isolates in total-gram8).
// Triangle cover bi<=bj (2080 blocks); diag blocks mask li>=lj ->
// rowsum == sum_neg. XCD swizzle: 260 blocks/XCD, FETCH floor ~67 MB.
__global__ __launch_bounds__(256, 4) void gram8_kernel(const u8* __restrict__ P8,
                                                       float* __restrict__ rowsum,
                                                       float* __restrict__ out,
                                                       unsigned int* __restrict__ ticket) {
    __shared__ u8 lds[5][8192];      // per buf: A tiles 0..3 @ a*1024, B @ 4096+
    const int t = threadIdx.x, w = t >> 6, lane = t & 63;

    // swizzled block -> (bi, bj), bi <= bj, 128-row strips
    int mm = blockIdx.x >> 3;
    const int r = blockIdx.x & 7;
    int bi = 0;
    #pragma unroll
    for (int s = 0; s < 8; ++s) {
        const int strip = (s & 1) ? ((s >> 1) * 16 + 15 - r) : ((s >> 1) * 16 + r);
        const int n = 64 - strip;
        if (mm < n) { bi = strip; break; }
        mm -= n;
    }
    const int bj = bi + mm;
    const bool diag = (bi == bj);

    // per-wave staging: 2 glds x 1 KB per chunk (A tile w, B tile w)
    const u8* gsrcA = P8 + (size_t)(bi * 4 + w) * 32768 + lane * 16;
    const u8* gsrcB = P8 + (size_t)(bj * 4 + w) * 32768 + lane * 16;
    const int ldsA = w * 1024, ldsB = 4096 + w * 1024;

    const int qi = w >> 1, qj = w & 1;
    const int aoff = qi * 2048 + lane * 8;          // A tile base within buf
    const int boff = 4096 + qj * 2048 + lane * 8;   // B tile base within buf

    f32x16 acc[2][2];
    #pragma unroll
    for (int a = 0; a < 2; ++a)
        #pragma unroll
        for (int b = 0; b < 2; ++b)
            #pragma unroll
            for (int e = 0; e < 16; ++e) acc[a][b][e] = 0.0f;

    long fa[2][2], fb[2][2];   // [reg set][tile]

#define STAGE(KC, BUF)                                                         \
    __builtin_amdgcn_global_load_lds(GLOBAL_AS(gsrcA + (size_t)(KC) * 1024),   \
                                     LDS_AS(&lds[BUF][ldsA]), 16, 0, 0);       \
    __builtin_amdgcn_global_load_lds(GLOBAL_AS(gsrcB + (size_t)(KC) * 1024),   \
                                     LDS_AS(&lds[BUF][ldsB]), 16, 0, 0);

#define PF(SET, BUF, KK)                                                       \
    fa[SET][0] = *(const long*)&lds[BUF][aoff + (KK) * 512];                   \
    fa[SET][1] = *(const long*)&lds[BUF][aoff + 1024 + (KK) * 512];            \
    fb[SET][0] = *(const long*)&lds[BUF][boff + (KK) * 512];                   \
    fb[SET][1] = *(const long*)&lds[BUF][boff + 1024 + (KK) * 512];

#define MFMA4(SET)                                                             \
    acc[0][0] = __builtin_amdgcn_mfma_f32_32x32x16_fp8_fp8(fa[SET][0], fb[SET][0], acc[0][0], 0, 0, 0); \
    acc[0][1] = __builtin_amdgcn_mfma_f32_32x32x16_fp8_fp8(fa[SET][0], fb[SET][1], acc[0][1], 0, 0, 0); \
    acc[1][0] = __builtin_amdgcn_mfma_f32_32x32x16_fp8_fp8(fa[SET][1], fb[SET][0], acc[1][0], 0, 0, 0); \
    acc[1][1] = __builtin_amdgcn_mfma_f32_32x32x16_fp8_fp8(fa[SET][1], fb[SET][1], acc[1][1], 0, 0, 0);

#define WAITV(N) asm volatile("s_waitcnt vmcnt(" #N ")" ::: "memory")
#define SP1 __builtin_amdgcn_s_setprio(1)
#define SP0 __builtin_amdgcn_s_setprio(0)

    // prologue: stage chunks 0..3 into bufs 0..3 (8 glds outstanding/wave)
    STAGE(0, 0); STAGE(1, 1); STAGE(2, 2); STAGE(3, 3);
    WAITV(4);                                // chunks 0,1 resident
    __builtin_amdgcn_s_barrier();
    PF(0, 0, 0);                             // step 0 (chunk 0, kk=0)

    int cb = 0;                              // buffer of chunk kc (kc % 5)
    for (int kc = 0; kc < 28; ++kc) {
        const int sb = (cb >= 1) ? cb - 1 : 4;       // (kc+4) % 5
        STAGE(kc + 4, sb);
        const int nb = (cb == 4) ? 0 : cb + 1;       // buffer of chunk kc+1
        PF(1, cb, 1);                        // step 2kc+1 (same chunk)
        SP1; MFMA4(0); SP0;                  // step 2kc
        PF(0, nb, 0);                        // step 2kc+2 (chunk kc+1 - certified)
        SP1; MFMA4(1); SP0;                  // step 2kc+1
        WAITV(4);                            // certifies chunks kc+1, kc+2
        __builtin_amdgcn_s_barrier();
        cb = nb;
    }
    // peeled tail (cb == 3): chunks 28..31 in bufs 3,4,0,1
    PF(1, 3, 1); SP1; MFMA4(0); SP0;         // steps 56/57
    PF(0, 4, 0); SP1; MFMA4(1); SP0;
    WAITV(2); __builtin_amdgcn_s_barrier();  // certifies chunk 30
    PF(1, 4, 1); SP1; MFMA4(0); SP0;         // steps 58/59
    PF(0, 0, 0); SP1; MFMA4(1); SP0;
    WAITV(0); __builtin_amdgcn_s_barrier();  // certifies chunk 31
    PF(1, 0, 1); SP1; MFMA4(0); SP0;         // steps 60/61
    PF(0, 1, 0); SP1; MFMA4(1); SP0;
    PF(1, 1, 1); SP1; MFMA4(0); SP0;         // steps 62/63
    SP1; MFMA4(1); SP0;

    // epilogue: exp(acc*10/64), diag-block triangle mask, row/col partials.
    // C layout (32x32): col = lane&31, row = (reg&3) + 8*(reg>>2) + 4*(lane>>5)
    __syncthreads();                         // K-loop fully done; lds reusable
    float* rpart = (float*)&lds[0][0];
    float* cpart = (float*)&lds[0][512];
    if (t < 128) { rpart[t] = 0.0f; cpart[t] = 0.0f; }
    __syncthreads();
    const int half = lane >> 5, col = lane & 31;
    float csum[2] = {0.0f, 0.0f};
    #pragma unroll
    for (int ti = 0; ti < 2; ++ti) {
        float rs[16];
        #pragma unroll
        for (int reg = 0; reg < 16; ++reg) rs[reg] = 0.0f;
        #pragma unroll
        for (int tj = 0; tj < 2; ++tj) {
            const int lj = qj * 64 + tj * 32 + col;
            #pragma unroll
            for (int reg = 0; reg < 16; ++reg) {
                const int li = qi * 64 + ti * 32 + (reg & 3) + 8 * (reg >> 2) + 4 * half;
                float e = __expf(acc[ti][tj][reg] * INVT_SCALED);
                if (diag && li >= lj) e = 0.0f;      // bi<bj blocks: always li<lj globally
                rs[reg] += e;
                csum[tj] += e;
            }
        }
        #pragma unroll
        for (int reg = 0; reg < 16; ++reg) {
            float v = rs[reg];
            v += __shfl_xor(v, 1); v += __shfl_xor(v, 2); v += __shfl_xor(v, 4);
            v += __shfl_xor(v, 8); v += __shfl_xor(v, 16);
            if (col == 0)
                atomicAdd(&rpart[qi * 64 + ti * 32 + (reg & 3) + 8 * (reg >> 2) + 4 * half], v);
        }
    }
    #pragma unroll
    for (int tj = 0; tj < 2; ++tj) {
        float v = csum[tj];
        v += __shfl_xor(v, 32);
        if (half == 0) atomicAdd(&cpart[qj * 64 + tj * 32 + col], v);
    }
    __syncthreads();
    if (t < 128) atomicAdd(&rowsum[bi * 128 + t], rpart[t]);
    else         atomicAdd(&rowsum[bj * 128 + (t - 128)], cpart[t - 128]);

    // ---- fused final reduction: last block to finish computes the loss ----
    __syncthreads();                         // all this block's atomics issued
    int* done = (int*)&lds[1][0];
    if (t == 0) {
        __threadfence();                     // release our rowsum adds
        unsigned int old = __hip_atomic_fetch_add(ticket, 1u, __ATOMIC_ACQ_REL,
                                                  __HIP_MEMORY_SCOPE_AGENT);
        *done = (old == (unsigned int)(NGRAM - 1));
    }
    __syncthreads();
    if (*done) {
        float s = 0.0f;
        for (int i = t; i < C; i += 256) {
            // agent-scope atomic load: coherent with the device atomicAdds
            float rv = __hip_atomic_load(&rowsum[i], __ATOMIC_RELAXED,
                                         __HIP_MEMORY_SCOPE_AGENT);
            s += logf(rv * (1.0f / (float)(C - 1)));
        }
        #pragma unroll
        for (int off = 32; off > 0; off >>= 1) s += __shfl_down(s, off);
        float* red = (float*)&lds[1][64];
        if ((t & 63) == 0) red[t >> 6] = s;
        __syncthreads();
        if (t == 0)
            out[0] = (red[0] + red[1] + red[2] + red[3]) * (1.0f / (float)C);
    }
}

// ---------------------------------------------------------------------------
extern "C" void kernel_launch(void* const* d_in, const int* in_sizes, int n_in,
                              void* d_out, int out_size, void* d_ws, size_t ws_size,
                              hipStream_t stream) {
    const float* feat = (const float*)d_in[0];
    const int* labels = (const int*)d_in[1];
    const float* protos = (const float*)d_in[2];
    float* out = (float*)d_out;
    float* rowsum = (float*)d_ws;               // 32 KB
    u8* P8 = (u8*)((char*)d_ws + 32768);        // 8 MiB packed fp8 protos
    unsigned int* ticket = (unsigned int*)((char*)d_ws + 32768 + 8388608);

    ema_split_kernel<<<C / 16, 256, 0, stream>>>(feat, labels, protos, P8, rowsum, out, ticket);
    gram8_kernel<<<NGRAM, 256, 0, stream>>>(P8, rowsum, out, ticket);
}

// Round 6
// 160.845 us; speedup vs baseline: 1.3747x; 1.3747x over previous
//
#include <hip/hip_runtime.h>
#include <math.h>

#define C 8192
#define D 1024
#define BATCH 1024
#define PM 0.95f
#define PMC 0.05f
// values pre-scaled by 8 before fp8 quant; dot comes out 64x too big.
// epilogue uses 10/64 = 0.15625 (exact in fp32).
#define INVT_SCALED 0.15625f

typedef unsigned char u8;
typedef __attribute__((ext_vector_type(16))) float f32x16;

#define GLOBAL_AS(p) ((const __attribute__((address_space(1))) void*)(p))
#define LDS_AS(p) ((__attribute__((address_space(3))) void*)(p))

// ---------------------------------------------------------------------------
// EMA + fp8 quantize (r17 exact, verified: 512 blocks x 16 consecutive
// classes, wave w owns classes cb+4w..cb+4w+3 sequentially; LDS-staged
// quantize + block-cooperative coalesced writeback so each 128-B P8 line is
// written once, fully, from one block/L2). fp8 layout (512-B k-units):
//   element (row c, k) -> P8[(c>>5)*32768 + (k>>4)*512 + ((k>>3)&1)*256 + (c&31)*8 + (k&7)]
__global__ __launch_bounds__(256) void ema_split_kernel(const float* __restrict__ feat,
                                                        const int* __restrict__ labels,
                                                        const float* __restrict__ protos,
                                                        u8* __restrict__ P8,
                                                        float* __restrict__ rowsum,
                                                        float* __restrict__ out) {
    __shared__ int sl[BATCH];
    __shared__ unsigned int sq[128][16][2];   // [piece][class-in-block][half]  16 KB
    const int t = threadIdx.x, w = t >> 6, lane = t & 63;
    const int cb = blockIdx.x * 16;

    if (blockIdx.x < 32) rowsum[blockIdx.x * 256 + t] = 0.0f;
    if (blockIdx.x == 0 && t == 0) out[0] = 0.0f;

    for (int i = t; i < BATCH; i += 256) sl[i] = labels[i];
    __syncthreads();

    for (int i = 0; i < 4; ++i) {
        const int c = cb + w * 4 + i;

        float4 v[4];
        #pragma unroll
        for (int s = 0; s < 4; ++s)
            v[s] = *(const float4*)(protos + (size_t)c * D + s * 256 + lane * 4);

        for (int base = 0; base < BATCH; base += 64) {
            unsigned long long mask = __ballot(sl[base + lane] == c);
            while (mask) {
                const int b = __ffsll((long long)mask) - 1;
                mask &= mask - 1;
                const int idx = base + b;
                float ss = 0.0f;
                #pragma unroll
                for (int s = 0; s < 4; ++s) {
                    const float4 f = *(const float4*)(feat + (size_t)idx * D + s * 256 + lane * 4);
                    v[s].x = v[s].x * PM + f.x * PMC;
                    v[s].y = v[s].y * PM + f.y * PMC;
                    v[s].z = v[s].z * PM + f.z * PMC;
                    v[s].w = v[s].w * PM + f.w * PMC;
                    ss += v[s].x * v[s].x + v[s].y * v[s].y + v[s].z * v[s].z + v[s].w * v[s].w;
                }
                #pragma unroll
                for (int off = 32; off > 0; off >>= 1) ss += __shfl_xor(ss, off);
                const float inv = 1.0f / fmaxf(sqrtf(ss), 1e-12f);
                #pragma unroll
                for (int s = 0; s < 4; ++s) {
                    v[s].x *= inv; v[s].y *= inv; v[s].z *= inv; v[s].w *= inv;
                }
            }
        }

        // quantize into LDS staging: piece pp = s*32 + (lane>>1), half = lane&1
        #pragma unroll
        for (int s = 0; s < 4; ++s) {
            int p = __builtin_amdgcn_cvt_pk_fp8_f32(v[s].x * 8.0f, v[s].y * 8.0f, 0, false);
            p = __builtin_amdgcn_cvt_pk_fp8_f32(v[s].z * 8.0f, v[s].w * 8.0f, p, true);
            sq[s * 32 + (lane >> 1)][w * 4 + i][lane & 1] = (unsigned int)p;
        }
    }
    __syncthreads();

    // coalesced writeback: 1024 slots of 16 B (piece pp, class pair 2a,2a+1)
    u8* base = P8 + (size_t)(cb >> 5) * 32768 + (cb & 31) * 8;
    #pragma unroll
    for (int it = 0; it < 4; ++it) {
        const int slot = it * 256 + t;
        const int pp = slot >> 3, a = slot & 7;
        uint4 val;
        val.x = sq[pp][2 * a][0];     val.y = sq[pp][2 * a][1];
        val.z = sq[pp][2 * a + 1][0]; val.w = sq[pp][2 * a + 1][1];
        *(uint4*)(base + (pp >> 1) * 512 + (pp & 1) * 256 + a * 16) = val;
    }
}

// ---------------------------------------------------------------------------
// fp8 Gram, mfma_f32_32x32x16_fp8_fp8.
//
// r19: LDS-BYTE REDUCTION. Post-mortem consolidation: bank conflicts 0 and
// every schedule rewrite (r14/r15/r16) was null-to-negative -> the K-loop is
// LDS-read-THROUGHPUT-bound: old 4-wave layout read 64 KB LDS per chunk per
// CU vs 256 MFMA-issue cyc/SIMD (~3:1 at ~85 B/cyc effective, = the 37%
// MfmaUtil). Fix: 2 waves per block, each owning a 64x128 output strip
// (2x4 grid of 32x32): per k-step a wave reads 2 A + 4 B frags for 8 MFMAs
// (vs 2+2 for 4) -> LDS bytes/chunk/CU 64->48 KB (-25%) at identical MFMA
// count, staging traffic, LDS footprint (40 KB, 4 blocks/CU) and ring depth.
// AGPR 128/wave + ~60 VGPR fits 2 waves/SIMD. Everything else is r13:
// 2080-block grid + XCD strip swizzle, 5-buffer ring, counted vmcnt (now
// WAITV(12): 4 glds/chunk/wave, 16 outstanding, oldest-4 = next chunk),
// one-barrier WAR separation. r18's per-block acq_rel ticket REMOVED
// (agent-scope acquire = L2 invalidate per block = 2x regression).
// Triangle cover bi<=bj; diag blocks mask li>=lj -> rowsum == sum_neg.
__global__ __launch_bounds__(128, 2) void gram8_kernel(const u8* __restrict__ P8,
                                                       float* __restrict__ rowsum) {
    __shared__ u8 lds[5][8192];      // per buf: A groups 0..3 @ g*1024, B @ 4096+
    const int t = threadIdx.x, w2 = t >> 6, lane = t & 63;

    // swizzled block -> (bi, bj), bi <= bj, 128-row strips
    int mm = blockIdx.x >> 3;
    const int r = blockIdx.x & 7;
    int bi = 0;
    #pragma unroll
    for (int s = 0; s < 8; ++s) {
        const int strip = (s & 1) ? ((s >> 1) * 16 + 15 - r) : ((s >> 1) * 16 + r);
        const int n = 64 - strip;
        if (mm < n) { bi = strip; break; }
        mm -= n;
    }
    const int bj = bi + mm;
    const bool diag = (bi == bj);

    // per-wave staging: 4 glds x 1 KB per chunk (A groups 2w2,2w2+1; B same)
    const u8* gA = P8 + (size_t)(bi * 4 + 2 * w2) * 32768 + lane * 16;
    const u8* gB = P8 + (size_t)(bj * 4 + 2 * w2) * 32768 + lane * 16;
    const int ldsA = 2 * w2 * 1024, ldsB = 4096 + 2 * w2 * 1024;

    const int aoff = w2 * 2048 + lane * 8;   // wave's A rows: groups 2w2,2w2+1
    const int boff = 4096 + lane * 8;        // B: all 4 groups

    f32x16 acc[2][4];
    #pragma unroll
    for (int a = 0; a < 2; ++a)
        #pragma unroll
        for (int b = 0; b < 4; ++b)
            #pragma unroll
            for (int e = 0; e < 16; ++e) acc[a][b][e] = 0.0f;

#define STAGE(KC, BUF)                                                         \
    __builtin_amdgcn_global_load_lds(GLOBAL_AS(gA + (size_t)(KC) * 1024),      \
                                     LDS_AS(&lds[BUF][ldsA]), 16, 0, 0);       \
    __builtin_amdgcn_global_load_lds(GLOBAL_AS(gA + (size_t)(KC) * 1024 + 32768), \
                                     LDS_AS(&lds[BUF][ldsA + 1024]), 16, 0, 0);   \
    __builtin_amdgcn_global_load_lds(GLOBAL_AS(gB + (size_t)(KC) * 1024),      \
                                     LDS_AS(&lds[BUF][ldsB]), 16, 0, 0);       \
    __builtin_amdgcn_global_load_lds(GLOBAL_AS(gB + (size_t)(KC) * 1024 + 32768), \
                                     LDS_AS(&lds[BUF][ldsB + 1024]), 16, 0, 0);

// consume one chunk (K=32 = 2 k-steps) from BUF: 12 ds_read_b64, 16 MFMAs
#define CHUNK(BUF)                                                             \
    {                                                                          \
        long fa0[2], fb0[4], fa1[2], fb1[4];                                   \
        fa0[0] = *(const long*)&lds[BUF][aoff];                                \
        fa0[1] = *(const long*)&lds[BUF][aoff + 1024];                         \
        fb0[0] = *(const long*)&lds[BUF][boff];                                \
        fb0[1] = *(const long*)&lds[BUF][boff + 1024];                         \
        fb0[2] = *(const long*)&lds[BUF][boff + 2048];                         \
        fb0[3] = *(const long*)&lds[BUF][boff + 3072];                         \
        fa1[0] = *(const long*)&lds[BUF][aoff + 512];                          \
        fa1[1] = *(const long*)&lds[BUF][aoff + 1536];                         \
        fb1[0] = *(const long*)&lds[BUF][boff + 512];                          \
        fb1[1] = *(const long*)&lds[BUF][boff + 1536];                         \
        fb1[2] = *(const long*)&lds[BUF][boff + 2560];                         \
        fb1[3] = *(const long*)&lds[BUF][boff + 3584];                         \
        _Pragma("unroll")                                                      \
        for (int j = 0; j < 4; ++j) {                                          \
            acc[0][j] = __builtin_amdgcn_mfma_f32_32x32x16_fp8_fp8(fa0[0], fb0[j], acc[0][j], 0, 0, 0); \
            acc[1][j] = __builtin_amdgcn_mfma_f32_32x32x16_fp8_fp8(fa0[1], fb0[j], acc[1][j], 0, 0, 0); \
        }                                                                      \
        _Pragma("unroll")                                                      \
        for (int j = 0; j < 4; ++j) {                                          \
            acc[0][j] = __builtin_amdgcn_mfma_f32_32x32x16_fp8_fp8(fa1[0], fb1[j], acc[0][j], 0, 0, 0); \
            acc[1][j] = __builtin_amdgcn_mfma_f32_32x32x16_fp8_fp8(fa1[1], fb1[j], acc[1][j], 0, 0, 0); \
        }                                                                      \
    }

#define WAITV(N) asm volatile("s_waitcnt vmcnt(" #N ")" ::: "memory")

    // prologue: stage chunks 0..3 into bufs 0..3 (16 glds outstanding/wave)
    STAGE(0, 0); STAGE(1, 1); STAGE(2, 2); STAGE(3, 3);
    WAITV(12);                               // chunk 0 resident
    __builtin_amdgcn_s_barrier();

    int cb = 0;                              // buffer of chunk kc (kc % 5)
    for (int kc = 0; kc < 28; ++kc) {
        const int sb = (cb >= 1) ? cb - 1 : 4;       // (kc+4)%5: held kc-1
        STAGE(kc + 4, sb);
        CHUNK(cb);
        WAITV(12);                           // certifies chunk kc+1
        __builtin_amdgcn_s_barrier();
        cb = (cb == 4) ? 0 : cb + 1;
    }
    // tail: chunks 28..31 in bufs 3,4,0,1 (no more staging)
    CHUNK(3); WAITV(8);  __builtin_amdgcn_s_barrier();   // certifies 29
    CHUNK(4); WAITV(4);  __builtin_amdgcn_s_barrier();   // certifies 30
    CHUNK(0); WAITV(0);  __builtin_amdgcn_s_barrier();   // certifies 31
    CHUNK(1);

    // epilogue: exp(acc*10/64), diag-block triangle mask, row/col partials.
    // C layout (32x32): col = lane&31, row = (reg&3) + 8*(reg>>2) + 4*(lane>>5)
    __syncthreads();                         // K-loop fully done; lds reusable
    float* rpart = (float*)&lds[0][0];
    float* cpart = (float*)&lds[0][512];
    rpart[t] = 0.0f; cpart[t] = 0.0f;
    __syncthreads();
    const int half = lane >> 5, col = lane & 31;
    float csum[4] = {0.0f, 0.0f, 0.0f, 0.0f};
    #pragma unroll
    for (int ti = 0; ti < 2; ++ti) {
        float rs[16];
        #pragma unroll
        for (int reg = 0; reg < 16; ++reg) rs[reg] = 0.0f;
        #pragma unroll
        for (int tj = 0; tj < 4; ++tj) {
            const int lj = tj * 32 + col;
            #pragma unroll
            for (int reg = 0; reg < 16; ++reg) {
                const int li = w2 * 64 + ti * 32 + (reg & 3) + 8 * (reg >> 2) + 4 * half;
                float e = __expf(acc[ti][tj][reg] * INVT_SCALED);
                if (diag && li >= lj) e = 0.0f;      // bi<bj blocks: always li<lj globally
                rs[reg] += e;
                csum[tj] += e;
            }
        }
        #pragma unroll
        for (int reg = 0; reg < 16; ++reg) {
            float v = rs[reg];
            v += __shfl_xor(v, 1); v += __shfl_xor(v, 2); v += __shfl_xor(v, 4);
            v += __shfl_xor(v, 8); v += __shfl_xor(v, 16);
            if (col == 0)
                atomicAdd(&rpart[w2 * 64 + ti * 32 + (reg & 3) + 8 * (reg >> 2) + 4 * half], v);
        }
    }
    #pragma unroll
    for (int tj = 0; tj < 4; ++tj) {
        float v = csum[tj];
        v += __shfl_xor(v, 32);
        if (half == 0) atomicAdd(&cpart[tj * 32 + col], v);
    }
    __syncthreads();
    atomicAdd(&rowsum[bi * 128 + t], rpart[t]);
    atomicAdd(&rowsum[bj * 128 + t], cpart[t]);
}

// ---------------------------------------------------------------------------
// rowsum == sum_neg (diag + lower triangle excluded in gram)
__global__ __launch_bounds__(256) void final2_kernel(const float* __restrict__ rowsum,
                                                     float* __restrict__ out) {
    __shared__ float red[4];
    const int t = threadIdx.x;
    const int i = blockIdx.x * 256 + t;
    float v = logf(rowsum[i] * (1.0f / (float)(C - 1)));
    #pragma unroll
    for (int off = 32; off > 0; off >>= 1) v += __shfl_down(v, off);
    if ((t & 63) == 0) red[t >> 6] = v;
    __syncthreads();
    if (t == 0)
        atomicAdd(out, (red[0] + red[1] + red[2] + red[3]) * (1.0f / (float)C));
}

// ---------------------------------------------------------------------------
extern "C" void kernel_launch(void* const* d_in, const int* in_sizes, int n_in,
                              void* d_out, int out_size, void* d_ws, size_t ws_size,
                              hipStream_t stream) {
    const float* feat = (const float*)d_in[0];
    const int* labels = (const int*)d_in[1];
    const float* protos = (const float*)d_in[2];
    float* out = (float*)d_out;
    float* rowsum = (float*)d_ws;               // 32 KB
    u8* P8 = (u8*)((char*)d_ws + 32768);        // 8 MiB packed fp8 protos

    ema_split_kernel<<<C / 16, 256, 0, stream>>>(feat, labels, protos, P8, rowsum, out);
    gram8_kernel<<<2080, 128, 0, stream>>>(P8, rowsum);
    final2_kernel<<<C / 256, 256, 0, stream>>>(rowsum, out);
}